// Round 1
// 625.562 us; speedup vs baseline: 1.0134x; 1.0134x over previous
//
#include <hip/hip_runtime.h>
#include <cstdint>

#define BB 16
#define NN 5000
#define FIN 32
#define DDF 64
#define JALL 320            // 64 critic + 128 alpha + 128 beta
#define KROWS 320000        // N*D
#define NCH 1000            // K-chunks for layer-1 MLP
#define CHROWS 320          // rows per chunk (= KROWS/NCH)

// ---------- special functions (f32, accurate ~1e-6 for x>1) ----------
__device__ __forceinline__ float softplusf_(float z){
  return z > 20.f ? z : log1pf(expf(z));
}
__device__ float gammalnf_(float x){
  float acc = 0.f;
  while (x < 8.f){ acc -= logf(x); x += 1.f; }
  float ix = 1.f/x, ix2 = ix*ix;
  return acc + (x-0.5f)*logf(x) - x + 0.91893853320467274f
       + ix*(8.3333333333333333e-2f + ix2*(-2.7777777777777778e-3f
       + ix2*(7.9365079365079365e-4f + ix2*(-5.9523809523809524e-4f))));
}
__device__ float digammaf_(float x){
  float acc = 0.f;
  while (x < 6.f){ acc -= 1.f/x; x += 1.f; }
  float ix = 1.f/x, ix2 = ix*ix;
  return acc + logf(x) - 0.5f*ix
       - ix2*(8.3333333333333333e-2f - ix2*(8.3333333333333333e-3f - ix2*3.968253968253968e-3f));
}

// ---------- CSR build ----------
__global__ void k_count(const int* __restrict__ ei, int* __restrict__ deg, int E){
  int e = blockIdx.x*256 + threadIdx.x;
  if (e < E) atomicAdd(&deg[ei[E+e]], 1);
}

__global__ __launch_bounds__(1024) void k_scan(const int* __restrict__ deg, int* __restrict__ offs,
                                               int* __restrict__ cursor, float* __restrict__ dinv){
  __shared__ int s[1024];
  int t = threadIdx.x;
  int v[5]; int sum = 0;
  int base = t*5;
  #pragma unroll
  for (int i=0;i<5;i++){ int idx=base+i; v[i] = (idx<NN) ? deg[idx] : 0; sum += v[i]; }
  s[t] = sum;
  __syncthreads();
  for (int off=1; off<1024; off<<=1){
    int add = (t>=off) ? s[t-off] : 0;
    __syncthreads();
    s[t] += add;
    __syncthreads();
  }
  int run = s[t] - sum;  // exclusive prefix of this chunk
  #pragma unroll
  for (int i=0;i<5;i++){
    int idx = base+i;
    if (idx < NN){
      offs[idx] = run; cursor[idx] = run;
      dinv[idx] = rsqrtf((float)(v[i]+1));   // +1 self-loop
      run += v[i];
    }
  }
  if (t==1023) offs[NN] = s[1023];
}

__global__ void k_fill(const int* __restrict__ ei, int* __restrict__ cursor,
                       int* __restrict__ csr, int E){
  int e = blockIdx.x*256 + threadIdx.x;
  if (e < E){
    int d = ei[E+e];
    int pos = atomicAdd(&cursor[d], 1);
    csr[pos] = ei[e];
  }
}

// ---------- GCN dense parts: ht[n][d][b] = dinv[n] * (in@W)[n][d][b] ----------
__global__ __launch_bounds__(256) void k_gemm1(const float* __restrict__ x, const float* __restrict__ W1,
                                               const float* __restrict__ dinv, float* __restrict__ ht){
  __shared__ float W1s[FIN*DDF];                    // 8 KB
  __shared__ alignas(16) float xs[4][FIN][20];      // pad 20: f4-aligned, conflict-free reads
  int t = threadIdx.x;
  int node0 = blockIdx.x*4;
  for (int i=t;i<FIN*DDF;i+=256) W1s[i] = W1[i];
  for (int i=t;i<4*16*FIN;i+=256){
    int ln = i>>9, rem = i&511, b = rem>>5, k = rem&31;
    xs[ln][k][b] = x[((size_t)b*NN + node0+ln)*FIN + k];
  }
  __syncthreads();
  int ln = t>>6, l = t&63;
  int d0 = (l&15)*4, b0 = (l>>4)*4;
  float acc[4][4] = {};
  for (int k=0;k<FIN;k++){
    const float4 wv = *(const float4*)&W1s[k*DDF + d0];
    const float4 xv = *(const float4*)&xs[ln][k][b0];
    float w[4]={wv.x,wv.y,wv.z,wv.w}, xr[4]={xv.x,xv.y,xv.z,xv.w};
    #pragma unroll
    for (int di=0;di<4;di++)
      #pragma unroll
      for (int bi=0;bi<4;bi++)
        acc[di][bi] = fmaf(w[di], xr[bi], acc[di][bi]);
  }
  int n = node0 + ln;
  float dn = dinv[n];
  float* op = &ht[(size_t)n*1024];
  #pragma unroll
  for (int di=0;di<4;di++){
    float4 o; o.x=acc[di][0]*dn; o.y=acc[di][1]*dn; o.z=acc[di][2]*dn; o.w=acc[di][3]*dn;
    *(float4*)&op[(d0+di)*16 + b0] = o;
  }
}

__global__ __launch_bounds__(256) void k_gemm2(const float* __restrict__ h1, const float* __restrict__ W2,
                                               const float* __restrict__ dinv, float* __restrict__ ht){
  __shared__ float W2s[DDF*DDF];        // 16 KB
  __shared__ float hs[4*1024];          // 16 KB, layout [node][k][b] (direct copy)
  int t = threadIdx.x;
  int node0 = blockIdx.x*4;
  for (int i=t;i<DDF*DDF;i+=256) W2s[i] = W2[i];
  const float4* src = (const float4*)&h1[(size_t)node0*1024];
  float4* dst4 = (float4*)hs;
  for (int i=t;i<1024;i+=256) dst4[i] = src[i];
  __syncthreads();
  int ln = t>>6, l = t&63;
  int d0 = (l&15)*4, b0 = (l>>4)*4;
  float acc[4][4] = {};
  for (int k=0;k<DDF;k++){
    const float4 wv = *(const float4*)&W2s[k*DDF + d0];
    const float4 xv = *(const float4*)&hs[ln*1024 + k*16 + b0];
    float w[4]={wv.x,wv.y,wv.z,wv.w}, xr[4]={xv.x,xv.y,xv.z,xv.w};
    #pragma unroll
    for (int di=0;di<4;di++)
      #pragma unroll
      for (int bi=0;bi<4;bi++)
        acc[di][bi] = fmaf(w[di], xr[bi], acc[di][bi]);
  }
  int n = node0 + ln;
  float dn = dinv[n];
  float* op = &ht[(size_t)n*1024];
  #pragma unroll
  for (int di=0;di<4;di++){
    float4 o; o.x=acc[di][0]*dn; o.y=acc[di][1]*dn; o.z=acc[di][2]*dn; o.w=acc[di][3]*dn;
    *(float4*)&op[(d0+di)*16 + b0] = o;
  }
}

// ---------- aggregation: out[n] = tanh(dinv[n]*(ht[n] + sum ht[src]) + bias[d]) ----------
__global__ __launch_bounds__(256) void k_agg(const float* __restrict__ ht, const int* __restrict__ csr,
                                             const int* __restrict__ offs, const float* __restrict__ dinv,
                                             const float* __restrict__ bias, float* __restrict__ out){
  int n = blockIdx.x, t = threadIdx.x;
  __shared__ int es[256];
  int beg = offs[n], end = offs[n+1];
  const float4 self = *(const float4*)&ht[(size_t)n*1024 + t*4];
  float ax = self.x, ay = self.y, az = self.z, aw = self.w;
  for (int base=beg; base<end; base+=256){
    int cnt = min(256, end-base);
    __syncthreads();
    if (t < cnt) es[t] = csr[base+t];
    __syncthreads();
    int j = 0;
    for (; j+4<=cnt; j+=4){
      const float4 v0 = *(const float4*)&ht[(size_t)es[j+0]*1024 + t*4];
      const float4 v1 = *(const float4*)&ht[(size_t)es[j+1]*1024 + t*4];
      const float4 v2 = *(const float4*)&ht[(size_t)es[j+2]*1024 + t*4];
      const float4 v3 = *(const float4*)&ht[(size_t)es[j+3]*1024 + t*4];
      ax += (v0.x+v1.x)+(v2.x+v3.x);
      ay += (v0.y+v1.y)+(v2.y+v3.y);
      az += (v0.z+v1.z)+(v2.z+v3.z);
      aw += (v0.w+v1.w)+(v2.w+v3.w);
    }
    for (; j<cnt; j++){
      const float4 v = *(const float4*)&ht[(size_t)es[j]*1024 + t*4];
      ax+=v.x; ay+=v.y; az+=v.z; aw+=v.w;
    }
  }
  float dn = dinv[n];
  float bb = bias[t>>2];     // inner = t*4 = d*16+b -> d = t>>2
  float4 o;
  o.x = tanhf(fmaf(dn, ax, bb));
  o.y = tanhf(fmaf(dn, ay, bb));
  o.z = tanhf(fmaf(dn, az, bb));
  o.w = tanhf(fmaf(dn, aw, bb));
  *(float4*)&out[(size_t)n*1024 + t*4] = o;
}

// ---------- fused MLP layer 1 ----------
// New structure: 1000 blocks x 320 threads (5 waves). Each wave owns one 64-wide
// j-tile; within a wave, lane = 16 jq x 4 bq -> acc is only 4 float4 (16 VGPR),
// leaving register room for ~8 in-flight W loads (the old version's 64-VGPR acc
// starved the load pipeline: 24% VALU + 24% HBM = latency-bound).
// The 4 bq groups read identical W bytes (merged by coalescer -> no extra HBM);
// obs is staged once per block into LDS (20 KB) and consumed via broadcast
// ds_reads, so obs is read from global exactly once total (was 5x).
// No cross-wave reduction: each wave writes disjoint partial columns.
#define FMA4(a,s,w) { a.x=fmaf(s,w.x,a.x); a.y=fmaf(s,w.y,a.y); a.z=fmaf(s,w.z,a.z); a.w=fmaf(s,w.w,a.w); }

template<int SJ>
__device__ __forceinline__ void mlp1_kloop(const float* __restrict__ Wp, const float* __restrict__ op,
                                           float4& a0, float4& a1, float4& a2, float4& a3){
  for (int it=0; it<CHROWS; it+=8){
    #pragma unroll
    for (int u=0; u<8; u++){
      int r = it + u;
      const float4 w = *(const float4*)&Wp[(size_t)r*SJ];
      const float4 o = *(const float4*)&op[r*16];
      FMA4(a0, o.x, w); FMA4(a1, o.y, w); FMA4(a2, o.z, w); FMA4(a3, o.w, w);
    }
  }
}

__global__ __launch_bounds__(320) void k_mlp1f(const float* __restrict__ Wc1,
    const float* __restrict__ Wa1, const float* __restrict__ Wb1,
    const float* __restrict__ obs, float* __restrict__ partial){
  __shared__ float obss[CHROWS*16];     // 20 KB: [row][b]
  int t = threadIdx.x;
  int chunk = blockIdx.x;
  {
    const float4* src = (const float4*)&obs[(size_t)chunk*CHROWS*16];
    float4* dst = (float4*)obss;
    #pragma unroll
    for (int i=0;i<4;i++) dst[i*320 + t] = src[i*320 + t];   // 1280 float4, coalesced
  }
  __syncthreads();

  int wv = t>>6, lane = t&63;
  int jq = lane&15, bq = lane>>4;
  const float* op = obss + bq*4;

  float4 a0,a1,a2,a3;
  a0 = a1 = a2 = a3 = make_float4(0.f,0.f,0.f,0.f);
  int cb;
  size_t rbase = (size_t)chunk*CHROWS;
  if (wv==0){
    cb = 0;   mlp1_kloop<64> (Wc1 + rbase*64  +      jq*4, op, a0,a1,a2,a3);
  } else if (wv==1){
    cb = 64;  mlp1_kloop<128>(Wa1 + rbase*128 +      jq*4, op, a0,a1,a2,a3);
  } else if (wv==2){
    cb = 128; mlp1_kloop<128>(Wa1 + rbase*128 + 64 + jq*4, op, a0,a1,a2,a3);
  } else if (wv==3){
    cb = 192; mlp1_kloop<128>(Wb1 + rbase*128 +      jq*4, op, a0,a1,a2,a3);
  } else {
    cb = 256; mlp1_kloop<128>(Wb1 + rbase*128 + 64 + jq*4, op, a0,a1,a2,a3);
  }

  float* dst = partial + (size_t)chunk*(BB*JALL) + cb + jq*4;
  *(float4*)&dst[(bq*4+0)*JALL] = a0;
  *(float4*)&dst[(bq*4+1)*JALL] = a1;
  *(float4*)&dst[(bq*4+2)*JALL] = a2;
  *(float4*)&dst[(bq*4+3)*JALL] = a3;
}

// ---------- two-stage partial reduce + bias + tanh -> act1[b][320] ----------
__global__ void k_red1(const float* __restrict__ partial, float* __restrict__ partial2){
  int o = blockIdx.x*256 + threadIdx.x;   // 0..5119
  int y = blockIdx.y;                     // 0..7
  int base = y*(NCH/8);
  float s0=0.f,s1=0.f,s2=0.f,s3=0.f,s4=0.f;
  for (int i=0;i<NCH/8;i+=5){
    s0 += partial[(size_t)(base+i+0)*(BB*JALL) + o];
    s1 += partial[(size_t)(base+i+1)*(BB*JALL) + o];
    s2 += partial[(size_t)(base+i+2)*(BB*JALL) + o];
    s3 += partial[(size_t)(base+i+3)*(BB*JALL) + o];
    s4 += partial[(size_t)(base+i+4)*(BB*JALL) + o];
  }
  partial2[(size_t)y*(BB*JALL) + o] = ((s0+s1)+(s2+s3))+s4;
}

__global__ void k_red2(const float* __restrict__ partial2, const float* __restrict__ bc1,
                       const float* __restrict__ ba1, const float* __restrict__ bb1,
                       float* __restrict__ act1){
  int o = blockIdx.x*256 + threadIdx.x;   // 0..5119
  float s = 0.f;
  #pragma unroll
  for (int y=0;y<8;y++) s += partial2[(size_t)y*(BB*JALL) + o];
  int col = o % JALL;
  float bias = col < 64 ? bc1[col] : (col < 192 ? ba1[col-64] : bb1[col-192]);
  act1[o] = tanhf(s + bias);
}

// ---------- tails: critic full, actor hidden layer 2 (batch-split over 4 blocks) ----------
__global__ __launch_bounds__(256) void k_tail(const float* __restrict__ act1,
    const float* __restrict__ Wc2, const float* __restrict__ bc2,
    const float* __restrict__ Wc3, const float* __restrict__ bc3,
    const float* __restrict__ Wa2, const float* __restrict__ ba2,
    const float* __restrict__ Wb2, const float* __restrict__ bb2,
    float* __restrict__ ah2, float* __restrict__ bh2, float* __restrict__ out){
  int t = threadIdx.x;
  if (blockIdx.x == 0){
    __shared__ float c1[16][64];
    __shared__ float c2[16][64];
    for (int i=t;i<16*64;i+=256) c1[i>>6][i&63] = act1[(i>>6)*JALL + (i&63)];
    __syncthreads();
    int j = t & 63, brow = t >> 6;
    for (int i=0;i<4;i++){
      int b = brow*4 + i;
      float s0 = bc2[j], s1 = 0.f;
      #pragma unroll 4
      for (int k=0;k<64;k+=2){
        s0 = fmaf(c1[b][k],   Wc2[k*64+j],     s0);
        s1 = fmaf(c1[b][k+1], Wc2[(k+1)*64+j], s1);
      }
      c2[b][j] = tanhf(s0+s1);
    }
    __syncthreads();
    if (t < 16){
      float s = bc3[0];
      for (int k=0;k<64;k++) s = fmaf(c2[t][k], Wc3[k], s);
      out[3*BB*NN + t] = s;   // value at offset 240000
    }
  } else {
    int which = (blockIdx.x-1) >> 1;      // 0 = alpha, 1 = beta
    int half  = (blockIdx.x-1) & 1;       // batch half: b in [half*8, half*8+8)
    const float* Wx2 = which ? Wb2 : Wa2;
    const float* bx2 = which ? bb2 : ba2;
    float* ox        = which ? bh2 : ah2;
    int cOff         = which ? 192 : 64;
    __shared__ float s1m[8][128];
    for (int i=t;i<8*128;i+=256) s1m[i>>7][i&127] = act1[(half*8 + (i>>7))*JALL + cOff + (i&127)];
    __syncthreads();
    int j = t & 127, bh = t >> 7;         // bh 0..1
    for (int i=0;i<4;i++){
      int bl = bh*4 + i;
      int b = half*8 + bl;
      float s0 = bx2[j], s1v = 0.f;
      #pragma unroll 4
      for (int k=0;k<128;k+=2){
        s0  = fmaf(s1m[bl][k],   Wx2[k*128+j],     s0);
        s1v = fmaf(s1m[bl][k+1], Wx2[(k+1)*128+j], s1v);
      }
      ox[b*128 + j] = tanhf(s0+s1v);
    }
  }
}

// ---------- final: actor layer 3 + Beta statistics ----------
__global__ __launch_bounds__(256) void k_final(const float* __restrict__ ah2, const float* __restrict__ bh2,
    const float* __restrict__ Wa3, const float* __restrict__ ba3,
    const float* __restrict__ Wb3, const float* __restrict__ bb3,
    float* __restrict__ out){
  __shared__ float as[128], bs[128];
  int t = threadIdx.x, b = blockIdx.y;
  if (t < 128){ as[t] = ah2[b*128+t]; bs[t] = bh2[b*128+t]; }
  __syncthreads();
  int n = blockIdx.x*256 + t;
  if (n >= NN) return;
  float sa = ba3[n], sb = bb3[n];
  #pragma unroll 4
  for (int k=0;k<128;k++){
    sa = fmaf(as[k], Wa3[k*NN+n], sa);
    sb = fmaf(bs[k], Wb3[k*NN+n], sb);
  }
  float alpha = 1.f + softplusf_(sa);
  float beta  = 1.f + softplusf_(sb);
  float action = alpha/(alpha+beta);
  float la = logf(action), lb = log1pf(-action);
  float logBt = gammalnf_(alpha) + gammalnf_(beta) - gammalnf_(alpha+beta);
  float logp = (alpha-1.f)*la + (beta-1.f)*lb - logBt;
  float ent = logBt - (alpha-1.f)*digammaf_(alpha) - (beta-1.f)*digammaf_(beta)
            + (alpha+beta-2.f)*digammaf_(alpha+beta);
  int o = b*NN + n;
  out[o]               = action;
  out[BB*NN + o]       = logp;
  out[2*BB*NN + o]     = ent;
}

extern "C" void kernel_launch(void* const* d_in, const int* in_sizes, int n_in,
                              void* d_out, int out_size, void* d_ws, size_t ws_size,
                              hipStream_t stream)
{
  const float* x   = (const float*)d_in[0];
  const int*   ei  = (const int*)d_in[1];
  const float* W1  = (const float*)d_in[2];
  const float* b1  = (const float*)d_in[3];
  const float* W2  = (const float*)d_in[4];
  const float* b2  = (const float*)d_in[5];
  const float* Wc1 = (const float*)d_in[6];
  const float* bc1 = (const float*)d_in[7];
  const float* Wc2 = (const float*)d_in[8];
  const float* bc2 = (const float*)d_in[9];
  const float* Wc3 = (const float*)d_in[10];
  const float* bc3 = (const float*)d_in[11];
  const float* Wa1 = (const float*)d_in[12];
  const float* ba1 = (const float*)d_in[13];
  const float* Wa2 = (const float*)d_in[14];
  const float* ba2 = (const float*)d_in[15];
  const float* Wa3 = (const float*)d_in[16];
  const float* ba3 = (const float*)d_in[17];
  const float* Wb1 = (const float*)d_in[18];
  const float* bb1 = (const float*)d_in[19];
  const float* Wb2 = (const float*)d_in[20];
  const float* bb2 = (const float*)d_in[21];
  const float* Wb3 = (const float*)d_in[22];
  const float* bb3 = (const float*)d_in[23];
  float* out = (float*)d_out;
  const int E = in_sizes[1]/2;

  char* p = (char*)d_ws;
  auto carve = [&](size_t bytes)->char*{ char* r = p; p += (bytes + 255) & ~(size_t)255; return r; };
  int*   deg      = (int*)carve((size_t)NN*4);
  int*   offs     = (int*)carve((size_t)(NN+1)*4);
  int*   cursor   = (int*)carve((size_t)NN*4);
  float* dinv     = (float*)carve((size_t)NN*4);
  int*   csr      = (int*)carve((size_t)E*4);
  float* partial2 = (float*)carve((size_t)8*BB*JALL*4);
  float* act1     = (float*)carve((size_t)BB*JALL*4);
  float* ah2      = (float*)carve((size_t)BB*128*4);
  float* bh2      = (float*)carve((size_t)BB*128*4);
  float* bufA     = (float*)carve((size_t)NN*1024*4);   // ht (pre-agg); later overlaid by partial
  float* bufB     = (float*)carve((size_t)NN*1024*4);   // h1, then obs_t
  float* partial  = bufA;   // NCH*BB*JALL*4 = 20,480,000 B == bufA size; bufA dead after 2nd k_agg

  hipMemsetAsync(deg, 0, (size_t)NN*4, stream);
  k_count<<<(E+255)/256, 256, 0, stream>>>(ei, deg, E);
  k_scan<<<1, 1024, 0, stream>>>(deg, offs, cursor, dinv);
  k_fill<<<(E+255)/256, 256, 0, stream>>>(ei, cursor, csr, E);

  k_gemm1<<<NN/4, 256, 0, stream>>>(x, W1, dinv, bufA);
  k_agg<<<NN, 256, 0, stream>>>(bufA, csr, offs, dinv, b1, bufB);
  k_gemm2<<<NN/4, 256, 0, stream>>>(bufB, W2, dinv, bufA);
  k_agg<<<NN, 256, 0, stream>>>(bufA, csr, offs, dinv, b2, bufB);   // bufB = obs_t[r][b]

  k_mlp1f<<<NCH, 320, 0, stream>>>(Wc1, Wa1, Wb1, bufB, partial);
  k_red1<<<dim3((BB*JALL)/256, 8), 256, 0, stream>>>(partial, partial2);
  k_red2<<<(BB*JALL)/256, 256, 0, stream>>>(partial2, bc1, ba1, bb1, act1);

  k_tail<<<5, 256, 0, stream>>>(act1, Wc2, bc2, Wc3, bc3, Wa2, ba2, Wb2, bb2, ah2, bh2, out);
  k_final<<<dim3(20, BB), 256, 0, stream>>>(ah2, bh2, Wa3, ba3, Wb3, bb3, out);
}